// Round 11
// baseline (2658.846 us; speedup 1.0000x reference)
//
#include <hip/hip_runtime.h>
#include <math.h>

#define NB 1000      // graphs
#define NN 100       // nodes per graph
#define EPG 1000     // edges per graph
#define FIN 14
#define HD 128
#define KP1 80
#define KP2 64
#define NT 512       // threads per block

// LDS float offsets (72 KB total)
#define O_HS   0                        // [100][128] = 12800
#define O_CB   12800                    // [100][32] = 3200 (alias xg[0:1600], ag[1600:3200])
#define O_SS   16000                    // 1000 ints: CSR sorted sources
#define O_RP   17000                    // 104 ints: rowptr
#define O_SC   17104                    // 100
#define O_MK1  17204                    // 100
#define O_MK2  17304                    // 100
#define O_P1   17404                    // 128
#define O_P2   17532                    // 128
#define O_ZSH  17660                    // 256
#define O_ZRD  17916                    // 512 floats (ints deg[0:128], pos[128:228] during CSR build)
#define O_INV  18428                    // 2
#define NSM    18430
#define SMEM_BYTES (NSM * 4)            // 73720 B

// Cross-round occupancy law (r5-r10): effective VGPR pool ~256/lane.
// VGPR=64 -> 4 waves/SIMD (43-46% occ); VGPR=120-128 -> 2 waves/SIMD (~23%).
// LDS is NOT binding (r5: 81.4KB ran 2 blocks/CU). VALU-issue total is
// ~150us invariant -> need 4 waves/SIMD + no spill. P4 live set cut to
// ~55 regs via k-group 2 (w[2]=8 regs, float2 A reads) to fit cap 64.
__global__ __launch_bounds__(NT, 4) void fused_gnn(
    const float* __restrict__ x, const int* __restrict__ ei,
    const float* __restrict__ Wrel1, const float* __restrict__ Wroot1,
    const float* __restrict__ b1, const float* __restrict__ p1,
    const float* __restrict__ Wrel2, const float* __restrict__ Wroot2,
    const float* __restrict__ b2, const float* __restrict__ p2,
    const float* __restrict__ l1w, const float* __restrict__ l1b,
    const float* __restrict__ l2w, const float* __restrict__ l2b,
    const float* __restrict__ l3w, const float* __restrict__ l3b,
    float* __restrict__ out)
{
    extern __shared__ float smf[];
    float* Hs  = smf + O_HS;
    float* CB  = smf + O_CB;
    float* xg  = CB;                 // [100][16] (cols 14,15 zero)
    float* ag  = CB + 1600;          // [100][16]
    int*   ssrc = (int*)(smf + O_SS);
    int*   rowptr = (int*)(smf + O_RP);
    float* sc  = smf + O_SC;
    float* mk1 = smf + O_MK1;
    float* mk2 = smf + O_MK2;
    float* p1s = smf + O_P1;
    float* p2s = smf + O_P2;
    float* zsh = smf + O_ZSH;
    float* zrd = smf + O_ZRD;
    int*   zdi = (int*)(smf + O_ZRD);   // deg[0:128] / pos[128:228] during build
    float* inv = smf + O_INV;

    const int tid = threadIdx.x;
    const int g = blockIdx.x;
    const int bn = g * NN;
    const int* srcp = ei + g * EPG;
    const int* dstp = ei + NB * EPG + g * EPG;

    // ---------- P0a: stage xg, zero ag, p vectors + norms, zero deg ----------
    for (int t = tid; t < 1600; t += NT) {
        int i = t >> 4, f = t & 15;
        xg[t] = (f < FIN) ? x[bn * FIN + i * FIN + f] : 0.f;
        ag[t] = 0.f;
    }
    if (tid < 128) { p1s[tid] = p1[tid]; p2s[tid] = p2[tid]; zdi[tid] = 0; }
    if (tid >= 256 && tid < 320) {
        int l = tid - 256;
        float a = p1[l], b = p1[l + 64];
        float v = a * a + b * b;
        for (int s = 1; s < 64; s <<= 1) v += __shfl_xor(v, s);
        if (l == 0) inv[0] = rsqrtf(v);
    } else if (tid >= 320 && tid < 384) {
        int l = tid - 320;
        float a = p2[l], b = p2[l + 64];
        float v = a * a + b * b;
        for (int s = 1; s < 64; s <<= 1) v += __shfl_xor(v, s);
        if (l == 0) inv[1] = rsqrtf(v);
    }
    __syncthreads();

    // ---------- P0b: CSR build — count ----------
    for (int e = tid; e < EPG; e += NT) {
        int dl = dstp[e] - bn;
        atomicAdd(&zdi[dl], 1);
    }
    __syncthreads();
    // ---------- P0c: exclusive scan via wave shfl (deg[0:128] -> rowptr) ----------
    if (tid < 64) {
        int a = zdi[tid], b = zdi[tid + 64];
        for (int off = 1; off < 64; off <<= 1) { int t = __shfl_up(a, off); if (tid >= off) a += t; }
        int totA = __shfl(a, 63);
        for (int off = 1; off < 64; off <<= 1) { int t = __shfl_up(b, off); if (tid >= off) b += t; }
        b += totA;
        rowptr[tid + 1] = a;          // inclusive -> rowptr[i+1]
        if (tid + 65 <= 103) rowptr[tid + 65] = b;
        if (tid == 0) rowptr[0] = 0;
    }
    __syncthreads();
    if (tid < NN) zdi[128 + tid] = rowptr[tid];       // pos cursors
    __syncthreads();
    // ---------- P0d: CSR scatter ----------
    for (int e = tid; e < EPG; e += NT) {
        int sl = srcp[e] - bn;
        int dl = dstp[e] - bn;
        int slot = atomicAdd(&zdi[128 + dl], 1);
        ssrc[slot] = sl;
    }
    __syncthreads();

    // ---------- P1: conv1 agg via CSR: ag[i][f] = sum_in-edges xg[src][f] ----------
    {
        const int f = tid & 15;
        if (f < FIN) {
            for (int i = tid >> 4; i < NN; i += 32) {
                int s0 = rowptr[i], s1 = rowptr[i + 1];
                float s = 0.f;
                for (int sl0 = s0; sl0 < s1; ++sl0)
                    s += xg[ssrc[sl0] * 16 + f];
                ag[i * 16 + f] = s;
            }
        }
    }
    __syncthreads();

    // ---------- P2: h1 = relu(ag@Wrel1 + xg@Wroot1 + b1) ----------
    {
        const int j = tid & 127;
        float wr[FIN], wo[FIN];
#pragma unroll
        for (int k = 0; k < FIN; ++k) { wr[k] = Wrel1[k * HD + j]; wo[k] = Wroot1[k * HD + j]; }
        const float bb = b1[j];
        for (int i = tid >> 7; i < NN; i += 4) {
            float s = bb;
#pragma unroll
            for (int k = 0; k < FIN; ++k)
                s += ag[i * 16 + k] * wr[k] + xg[i * 16 + k] * wo[k];
            Hs[i * HD + j] = fmaxf(s, 0.f);
        }
    }
    __syncthreads();

    // ---------- P3: pool1 score + top-80 + scale + readout1 ----------
    if (tid < 400) {
        const int row = tid >> 2, q = tid & 3;
        float d = 0.f;
        for (int kk = 0; kk < 32; ++kk) {
            int k = q * 32 + ((kk + tid) & 31);
            d += Hs[row * HD + k] * p1s[k];
        }
        d += __shfl_xor(d, 1);
        d += __shfl_xor(d, 2);
        if (q == 0) sc[row] = tanhf(d * inv[0]);
    }
    __syncthreads();
    if (tid < 400) {                    // rank-count, 4 lanes/row
        const int row = tid >> 2, q = tid & 3;
        float si = sc[row]; int cnt = 0;
        for (int j2 = q * 25; j2 < q * 25 + 25; ++j2) cnt += (sc[j2] > si) ? 1 : 0;
        cnt += __shfl_xor(cnt, 1);
        cnt += __shfl_xor(cnt, 2);
        if (q == 0) mk1[row] = (cnt < KP1) ? 1.f : 0.f;
    }
    __syncthreads();
    for (int o = tid; o < NN * HD; o += NT) { int i = o >> 7; Hs[o] *= sc[i] * mk1[i]; }
    __syncthreads();
    {
        const int col = tid & 127, ch = tid >> 7;
        float mean = 0.f, mx = -1e30f;
        for (int i = ch * 25; i < ch * 25 + 25; ++i) {
            float v = Hs[i * HD + col];
            mean += v;
            if (mk1[i] > 0.f && v > mx) mx = v;
        }
        zrd[tid] = mean; CB[tid] = mx;
    }
    __syncthreads();
    if (tid < HD) {
        float mean = zrd[tid] + zrd[128 + tid] + zrd[256 + tid] + zrd[384 + tid];
        float mx = fmaxf(fmaxf(CB[tid], CB[128 + tid]), fmaxf(CB[256 + tid], CB[384 + tid]));
        zsh[tid] = mean * (1.f / KP1);
        zsh[HD + tid] = mx;
    }

    // ---------- P4: conv2: acc = b2 + Hs@Wroot2 + sum_c CSRagg@Wrel2 ----------
    const int tr = tid >> 5, tc = tid & 31;     // 16 row-groups x 32 col-groups
    const int i0 = tr * 7, j0 = tc * 4;
    const float4* Wrel2v  = (const float4*)Wrel2;
    const float4* Wroot2v = (const float4*)Wroot2;

    int rowc[7];                                 // clamped read rows (stores guarded)
#pragma unroll
    for (int r = 0; r < 7; ++r) rowc[r] = (i0 + r < NN) ? (i0 + r) : (NN - 1);

    float acc[7][4];
    {
        float4 bv = ((const float4*)b2)[tc];
#pragma unroll
        for (int r = 0; r < 7; ++r) { acc[r][0] = bv.x; acc[r][1] = bv.y; acc[r][2] = bv.z; acc[r][3] = bv.w; }
    }
    // root pass: k-group 2 (w[2]=8 regs live, float2 A reads) — fits cap 64
    for (int k0 = 0; k0 < HD; k0 += 2) {
        float4 w0 = Wroot2v[k0 * 32 + tc];
        float4 w1 = Wroot2v[(k0 + 1) * 32 + tc];
#pragma unroll
        for (int r = 0; r < 7; ++r) {
            float2 a = *(const float2*)&Hs[rowc[r] * HD + k0];
            acc[r][0] += a.x * w0.x + a.y * w1.x;
            acc[r][1] += a.x * w0.y + a.y * w1.y;
            acc[r][2] += a.x * w0.z + a.y * w1.z;
            acc[r][3] += a.x * w0.w + a.y * w1.w;
        }
    }
    // rel pass: 4 chunks of 32 cols; CSR gather (no atomics) then k-group-2 FMA
    for (int c = 0; c < 4; ++c) {
        __syncthreads();                     // prior CB readers done
        {
            const int jj = tid & 31;
            const int cb = c * 32 + jj;
            for (int i = tid >> 5; i < NN; i += 16) {
                int s0 = rowptr[i], s1 = rowptr[i + 1];
                float s = 0.f;
                for (int sl0 = s0; sl0 < s1; ++sl0)
                    s += Hs[ssrc[sl0] * HD + cb];
                CB[i * 32 + jj] = s;
            }
        }
        __syncthreads();
        for (int kk0 = 0; kk0 < 32; kk0 += 2) {
            float4 w0 = Wrel2v[(c * 32 + kk0) * 32 + tc];
            float4 w1 = Wrel2v[(c * 32 + kk0 + 1) * 32 + tc];
#pragma unroll
            for (int r = 0; r < 7; ++r) {
                float2 a = *(const float2*)&CB[rowc[r] * 32 + kk0];
                acc[r][0] += a.x * w0.x + a.y * w1.x;
                acc[r][1] += a.x * w0.y + a.y * w1.y;
                acc[r][2] += a.x * w0.z + a.y * w1.z;
                acc[r][3] += a.x * w0.w + a.y * w1.w;
            }
        }
    }
    __syncthreads();                          // all readers of Hs done
    // write h2 = relu(acc) into Hs, guarded
#pragma unroll
    for (int r = 0; r < 7; ++r) {
        if (i0 + r < NN) {
            float4 v;
            v.x = fmaxf(acc[r][0], 0.f); v.y = fmaxf(acc[r][1], 0.f);
            v.z = fmaxf(acc[r][2], 0.f); v.w = fmaxf(acc[r][3], 0.f);
            *(float4*)&Hs[(i0 + r) * HD + j0] = v;
        }
    }
    __syncthreads();

    // ---------- P5: pool2 + readout2 ----------
    if (tid < 400) {
        const int row = tid >> 2, q = tid & 3;
        float d = 0.f;
        for (int kk = 0; kk < 32; ++kk) {
            int k = q * 32 + ((kk + tid) & 31);
            d += Hs[row * HD + k] * p2s[k];
        }
        d += __shfl_xor(d, 1);
        d += __shfl_xor(d, 2);
        if (q == 0) sc[row] = (mk1[row] > 0.f) ? tanhf(d * inv[1]) : -1e30f;
    }
    __syncthreads();
    if (tid < 400) {                    // rank-count, 4 lanes/row
        const int row = tid >> 2, q = tid & 3;
        float si = sc[row]; int cnt = 0;
        for (int j2 = q * 25; j2 < q * 25 + 25; ++j2) cnt += (sc[j2] > si) ? 1 : 0;
        cnt += __shfl_xor(cnt, 1);
        cnt += __shfl_xor(cnt, 2);
        if (q == 0) mk2[row] = (mk1[row] > 0.f && cnt < KP2) ? 1.f : 0.f;
    }
    __syncthreads();
    for (int o = tid; o < NN * HD; o += NT) { int i = o >> 7; Hs[o] *= sc[i] * mk2[i]; }
    __syncthreads();
    {
        const int col = tid & 127, ch = tid >> 7;
        float mean = 0.f, mx = -1e30f;
        for (int i = ch * 25; i < ch * 25 + 25; ++i) {
            float v = Hs[i * HD + col];
            mean += v;
            if (mk2[i] > 0.f && v > mx) mx = v;
        }
        zrd[tid] = mean; CB[tid] = mx;
    }
    __syncthreads();
    if (tid < HD) {
        float mean = zrd[tid] + zrd[128 + tid] + zrd[256 + tid] + zrd[384 + tid];
        float mx = fmaxf(fmaxf(CB[tid], CB[128 + tid]), fmaxf(CB[256 + tid], CB[384 + tid]));
        zsh[tid] += mean * (1.f / KP2);
        zsh[HD + tid] += mx;
    }
    __syncthreads();

    // ---------- P6: MLP + log_softmax (z1 -> CB[0:128], z2 -> CB[256:288]) ----------
    {   // l1: 256 -> 128, k split over 4 chunks of 64
        const int j = tid & 127, q = tid >> 7;
        float a = 0.f;
        for (int kk = 0; kk < 64; ++kk) {
            int k = q * 64 + kk;
            a += zsh[k] * l1w[k * HD + j];
        }
        zrd[tid] = a;
    }
    __syncthreads();
    if (tid < HD)
        CB[tid] = fmaxf(zrd[tid] + zrd[128 + tid] + zrd[256 + tid] + zrd[384 + tid] + l1b[tid], 0.f);
    __syncthreads();
    if (tid < 256) {   // l2: 128 -> 32, k split over 8 chunks of 16
        const int o = tid & 31, q = tid >> 5;
        float a = 0.f;
        for (int kk = 0; kk < 16; ++kk) {
            int k = q * 16 + kk;
            a += CB[k] * l2w[k * 32 + o];
        }
        zrd[tid] = a;
    }
    __syncthreads();
    if (tid < 32) {
        float v = l2b[tid];
#pragma unroll
        for (int q = 0; q < 8; ++q) v += zrd[q * 32 + tid];
        CB[256 + tid] = fmaxf(v, 0.f);
    }
    __syncthreads();
    if (tid == 0) {
        float o0 = l3b[0], o1 = l3b[1];
        for (int k = 0; k < 32; ++k) {
            float v = CB[256 + k];
            o0 += v * l3w[2 * k];
            o1 += v * l3w[2 * k + 1];
        }
        float m = fmaxf(o0, o1);
        float l = m + logf(expf(o0 - m) + expf(o1 - m));
        out[g * 2 + 0] = o0 - l;
        out[g * 2 + 1] = o1 - l;
    }
}

extern "C" void kernel_launch(void* const* d_in, const int* in_sizes, int n_in,
                              void* d_out, int out_size, void* d_ws, size_t ws_size,
                              hipStream_t stream)
{
    const float* x      = (const float*)d_in[0];
    const int*   ei     = (const int*)d_in[1];
    const float* Wrel1  = (const float*)d_in[2];
    const float* Wroot1 = (const float*)d_in[3];
    const float* b1     = (const float*)d_in[4];
    const float* p1     = (const float*)d_in[5];
    const float* Wrel2  = (const float*)d_in[6];
    const float* Wroot2 = (const float*)d_in[7];
    const float* b2     = (const float*)d_in[8];
    const float* p2     = (const float*)d_in[9];
    const float* l1w    = (const float*)d_in[10];
    const float* l1b    = (const float*)d_in[11];
    const float* l2w    = (const float*)d_in[12];
    const float* l2b    = (const float*)d_in[13];
    const float* l3w    = (const float*)d_in[14];
    const float* l3b    = (const float*)d_in[15];
    float* out = (float*)d_out;

    (void)hipFuncSetAttribute((const void*)fused_gnn,
                              hipFuncAttributeMaxDynamicSharedMemorySize, SMEM_BYTES);

    fused_gnn<<<dim3(NB), dim3(NT), SMEM_BYTES, stream>>>(
        x, ei, Wrel1, Wroot1, b1, p1, Wrel2, Wroot2, b2, p2,
        l1w, l1b, l2w, l2b, l3w, l3b, out);
}

// Round 12
// 284.791 us; speedup vs baseline: 9.3361x; 9.3361x over previous
//
#include <hip/hip_runtime.h>
#include <math.h>

#define NB 1000      // graphs
#define NN 100       // nodes per graph
#define EPG 1000     // edges per graph
#define FIN 14
#define HD 128
#define KP1 80
#define KP2 64
#define NT 512       // threads per block

// LDS float offsets (141.5 KB total; 1 block/CU — VGPR already caps us there)
#define O_HS   0                        // [100][128] = 12800
#define O_CB   12800                    // [100][128] = 12800 (alias xg[0:1600], ag[1600:3200] in conv1)
#define O_WL   25600                    // [64][128] = 8192 (W staging half)
#define O_SS   33792                    // 1000 ints: CSR sorted sources
#define O_RP   34792                    // 104 ints: rowptr
#define O_SC   34896                    // 100
#define O_MK1  34996                    // 100
#define O_MK2  35096                    // 100
#define O_P1   35196                    // 128
#define O_P2   35324                    // 128
#define O_ZSH  35452                    // 256
#define O_ZRD  35708                    // 512 floats (ints deg[0:128], pos[128:228] during CSR build)
#define O_INV  36220                    // 2
#define NSM    36222
#define SMEM_BYTES (NSM * 4)            // 144888 B

// Cross-round laws (r5-r11):
//  - cap-64 ((512,4)) ALWAYS spills catastrophically for this kernel
//    (4 attempts: 143MB..7.7GB scratch traffic). Cap-128 ((512,2)) = zero
//    spill (r6 VGPR=120, r10 VGPR=128, WRITE 31KB).
//  - VGPR=128 -> 2 waves/SIMD (~23% occ) regardless of LDS -> 1 block/CU,
//    so all 160KB LDS is ours. Lever = per-wave ILP: W staged in LDS
//    (no L2 latency in inner loop), CSR gather once full-width (b128).
__global__ __launch_bounds__(NT, 2) void fused_gnn(
    const float* __restrict__ x, const int* __restrict__ ei,
    const float* __restrict__ Wrel1, const float* __restrict__ Wroot1,
    const float* __restrict__ b1, const float* __restrict__ p1,
    const float* __restrict__ Wrel2, const float* __restrict__ Wroot2,
    const float* __restrict__ b2, const float* __restrict__ p2,
    const float* __restrict__ l1w, const float* __restrict__ l1b,
    const float* __restrict__ l2w, const float* __restrict__ l2b,
    const float* __restrict__ l3w, const float* __restrict__ l3b,
    float* __restrict__ out)
{
    extern __shared__ float smf[];
    float* Hs  = smf + O_HS;
    float* CB  = smf + O_CB;
    float* Wl  = smf + O_WL;
    float* xg  = CB;                 // [100][16] (cols 14,15 zero)
    float* ag  = CB + 1600;          // [100][16]
    int*   ssrc = (int*)(smf + O_SS);
    int*   rowptr = (int*)(smf + O_RP);
    float* sc  = smf + O_SC;
    float* mk1 = smf + O_MK1;
    float* mk2 = smf + O_MK2;
    float* p1s = smf + O_P1;
    float* p2s = smf + O_P2;
    float* zsh = smf + O_ZSH;
    float* zrd = smf + O_ZRD;
    int*   zdi = (int*)(smf + O_ZRD);   // deg[0:128] / pos[128:228] during build
    float* inv = smf + O_INV;

    const int tid = threadIdx.x;
    const int g = blockIdx.x;
    const int bn = g * NN;
    const int* srcp = ei + g * EPG;
    const int* dstp = ei + NB * EPG + g * EPG;

    // ---------- P0a: stage xg, zero ag, p vectors + norms, zero deg ----------
    for (int t = tid; t < 1600; t += NT) {
        int i = t >> 4, f = t & 15;
        xg[t] = (f < FIN) ? x[bn * FIN + i * FIN + f] : 0.f;
        ag[t] = 0.f;
    }
    if (tid < 128) { p1s[tid] = p1[tid]; p2s[tid] = p2[tid]; zdi[tid] = 0; }
    if (tid >= 256 && tid < 320) {
        int l = tid - 256;
        float a = p1[l], b = p1[l + 64];
        float v = a * a + b * b;
        for (int s = 1; s < 64; s <<= 1) v += __shfl_xor(v, s);
        if (l == 0) inv[0] = rsqrtf(v);
    } else if (tid >= 320 && tid < 384) {
        int l = tid - 320;
        float a = p2[l], b = p2[l + 64];
        float v = a * a + b * b;
        for (int s = 1; s < 64; s <<= 1) v += __shfl_xor(v, s);
        if (l == 0) inv[1] = rsqrtf(v);
    }
    __syncthreads();

    // ---------- P0b: CSR build — count ----------
    for (int e = tid; e < EPG; e += NT) {
        int dl = dstp[e] - bn;
        atomicAdd(&zdi[dl], 1);
    }
    __syncthreads();
    // ---------- P0c: exclusive scan via wave shfl (deg[0:128] -> rowptr) ----------
    if (tid < 64) {
        int a = zdi[tid], b = zdi[tid + 64];
        for (int off = 1; off < 64; off <<= 1) { int t = __shfl_up(a, off); if (tid >= off) a += t; }
        int totA = __shfl(a, 63);
        for (int off = 1; off < 64; off <<= 1) { int t = __shfl_up(b, off); if (tid >= off) b += t; }
        b += totA;
        rowptr[tid + 1] = a;          // inclusive -> rowptr[i+1]
        if (tid + 65 <= 103) rowptr[tid + 65] = b;
        if (tid == 0) rowptr[0] = 0;
    }
    __syncthreads();
    if (tid < NN) zdi[128 + tid] = rowptr[tid];       // pos cursors
    __syncthreads();
    // ---------- P0d: CSR scatter ----------
    for (int e = tid; e < EPG; e += NT) {
        int sl = srcp[e] - bn;
        int dl = dstp[e] - bn;
        int slot = atomicAdd(&zdi[128 + dl], 1);
        ssrc[slot] = sl;
    }
    __syncthreads();

    // ---------- P1: conv1 agg via CSR: ag[i][f] = sum_in-edges xg[src][f] ----------
    {
        const int f = tid & 15;
        if (f < FIN) {
            for (int i = tid >> 4; i < NN; i += 32) {
                int s0 = rowptr[i], s1 = rowptr[i + 1];
                float s = 0.f;
                for (int sl0 = s0; sl0 < s1; ++sl0)
                    s += xg[ssrc[sl0] * 16 + f];
                ag[i * 16 + f] = s;
            }
        }
    }
    __syncthreads();

    // ---------- P2: h1 = relu(ag@Wrel1 + xg@Wroot1 + b1) ----------
    {
        const int j = tid & 127;
        float wr[FIN], wo[FIN];
#pragma unroll
        for (int k = 0; k < FIN; ++k) { wr[k] = Wrel1[k * HD + j]; wo[k] = Wroot1[k * HD + j]; }
        const float bb = b1[j];
        for (int i = tid >> 7; i < NN; i += 4) {
            float s = bb;
#pragma unroll
            for (int k = 0; k < FIN; ++k)
                s += ag[i * 16 + k] * wr[k] + xg[i * 16 + k] * wo[k];
            Hs[i * HD + j] = fmaxf(s, 0.f);
        }
    }
    __syncthreads();

    // ---------- P3: pool1 score + top-80 + scale + readout1 ----------
    if (tid < 400) {
        const int row = tid >> 2, q = tid & 3;
        float d = 0.f;
        for (int kk = 0; kk < 32; ++kk) {
            int k = q * 32 + ((kk + tid) & 31);
            d += Hs[row * HD + k] * p1s[k];
        }
        d += __shfl_xor(d, 1);
        d += __shfl_xor(d, 2);
        if (q == 0) sc[row] = tanhf(d * inv[0]);
    }
    __syncthreads();
    if (tid < 400) {                    // rank-count, 4 lanes/row
        const int row = tid >> 2, q = tid & 3;
        float si = sc[row]; int cnt = 0;
        for (int j2 = q * 25; j2 < q * 25 + 25; ++j2) cnt += (sc[j2] > si) ? 1 : 0;
        cnt += __shfl_xor(cnt, 1);
        cnt += __shfl_xor(cnt, 2);
        if (q == 0) mk1[row] = (cnt < KP1) ? 1.f : 0.f;
    }
    __syncthreads();
    for (int o = tid; o < NN * HD; o += NT) { int i = o >> 7; Hs[o] *= sc[i] * mk1[i]; }
    __syncthreads();
    {
        const int col = tid & 127, ch = tid >> 7;
        float mean = 0.f, mx = -1e30f;
        for (int i = ch * 25; i < ch * 25 + 25; ++i) {
            float v = Hs[i * HD + col];
            mean += v;
            if (mk1[i] > 0.f && v > mx) mx = v;
        }
        zrd[tid] = mean; CB[tid] = mx;
    }
    __syncthreads();
    if (tid < HD) {
        float mean = zrd[tid] + zrd[128 + tid] + zrd[256 + tid] + zrd[384 + tid];
        float mx = fmaxf(fmaxf(CB[tid], CB[128 + tid]), fmaxf(CB[256 + tid], CB[384 + tid]));
        zsh[tid] = mean * (1.f / KP1);
        zsh[HD + tid] = mx;
    }
    // (combine above reads CB[0:512]; nothing below writes CB before the
    //  gather, which sits behind two barriers)

    // ---------- P4: conv2 with W staged in LDS ----------
    const int tr = tid >> 5, tc = tid & 31;     // 16 row-groups x 32 col-groups
    const int i0 = tr * 7, j0 = tc * 4;

    int rowc[7];                                 // clamped read rows (stores guarded)
#pragma unroll
    for (int r = 0; r < 7; ++r) rowc[r] = (i0 + r < NN) ? (i0 + r) : (NN - 1);

    float acc[7][4];
    {
        float4 bv = ((const float4*)b2)[tc];
#pragma unroll
        for (int r = 0; r < 7; ++r) { acc[r][0] = bv.x; acc[r][1] = bv.y; acc[r][2] = bv.z; acc[r][3] = bv.w; }
    }

#define STAGE_W(SRC, HALF)                                                  \
    for (int t = tid; t < 2048; t += NT)                                    \
        ((float4*)Wl)[t] = ((const float4*)(SRC))[(HALF) * 2048 + t];

#define CONV2_FMA_HALF(ABASE, KOFF)                                         \
    for (int k0 = 0; k0 < 64; k0 += 4) {                                    \
        const float* wl = Wl + k0 * HD + j0;                                \
        float4 w0 = *(const float4*)(wl);                                   \
        float4 w1 = *(const float4*)(wl + HD);                              \
        float4 w2 = *(const float4*)(wl + 2 * HD);                          \
        float4 w3 = *(const float4*)(wl + 3 * HD);                          \
        _Pragma("unroll")                                                   \
        for (int r = 0; r < 7; ++r) {                                       \
            float4 a = *(const float4*)&ABASE[rowc[r] * HD + (KOFF) + k0];  \
            acc[r][0] += a.x * w0.x + a.y * w1.x + a.z * w2.x + a.w * w3.x; \
            acc[r][1] += a.x * w0.y + a.y * w1.y + a.z * w2.y + a.w * w3.y; \
            acc[r][2] += a.x * w0.z + a.y * w1.z + a.z * w2.z + a.w * w3.z; \
            acc[r][3] += a.x * w0.w + a.y * w1.w + a.z * w2.w + a.w * w3.w; \
        }                                                                   \
    }

    // ROOT pass: acc += Hs @ Wroot2, staged in two 64-row halves
    STAGE_W(Wroot2, 0);
    __syncthreads();                 // stage visible; P3 combine also done
    CONV2_FMA_HALF(Hs, 0)
    __syncthreads();                 // Wl readers done
    STAGE_W(Wroot2, 1);
    __syncthreads();
    CONV2_FMA_HALF(Hs, 64)
    __syncthreads();                 // Wl readers done; CB[0:512] readers long done

    // REL pass: gather CB = Adj@Hs full-width (once), stage Wrel2 half 0
    for (int t = tid; t < NN * 32; t += NT) {
        int i = t >> 5, jj = t & 31;
        int s0 = rowptr[i], s1 = rowptr[i + 1];
        float4 s = {0.f, 0.f, 0.f, 0.f};
        for (int e = s0; e < s1; ++e) {
            const float4 v = *(const float4*)&Hs[ssrc[e] * HD + 4 * jj];
            s.x += v.x; s.y += v.y; s.z += v.z; s.w += v.w;
        }
        *(float4*)&CB[i * HD + 4 * jj] = s;
    }
    STAGE_W(Wrel2, 0);
    __syncthreads();
    CONV2_FMA_HALF(CB, 0)
    __syncthreads();
    STAGE_W(Wrel2, 1);
    __syncthreads();
    CONV2_FMA_HALF(CB, 64)
    __syncthreads();                 // all reads of Hs/CB/Wl done

    // write h2 = relu(acc) into Hs, guarded
#pragma unroll
    for (int r = 0; r < 7; ++r) {
        if (i0 + r < NN) {
            float4 v;
            v.x = fmaxf(acc[r][0], 0.f); v.y = fmaxf(acc[r][1], 0.f);
            v.z = fmaxf(acc[r][2], 0.f); v.w = fmaxf(acc[r][3], 0.f);
            *(float4*)&Hs[(i0 + r) * HD + j0] = v;
        }
    }
    __syncthreads();

    // ---------- P5: pool2 + readout2 ----------
    if (tid < 400) {
        const int row = tid >> 2, q = tid & 3;
        float d = 0.f;
        for (int kk = 0; kk < 32; ++kk) {
            int k = q * 32 + ((kk + tid) & 31);
            d += Hs[row * HD + k] * p2s[k];
        }
        d += __shfl_xor(d, 1);
        d += __shfl_xor(d, 2);
        if (q == 0) sc[row] = (mk1[row] > 0.f) ? tanhf(d * inv[1]) : -1e30f;
    }
    __syncthreads();
    if (tid < 400) {                    // rank-count, 4 lanes/row
        const int row = tid >> 2, q = tid & 3;
        float si = sc[row]; int cnt = 0;
        for (int j2 = q * 25; j2 < q * 25 + 25; ++j2) cnt += (sc[j2] > si) ? 1 : 0;
        cnt += __shfl_xor(cnt, 1);
        cnt += __shfl_xor(cnt, 2);
        if (q == 0) mk2[row] = (mk1[row] > 0.f && cnt < KP2) ? 1.f : 0.f;
    }
    __syncthreads();
    for (int o = tid; o < NN * HD; o += NT) { int i = o >> 7; Hs[o] *= sc[i] * mk2[i]; }
    __syncthreads();
    {
        const int col = tid & 127, ch = tid >> 7;
        float mean = 0.f, mx = -1e30f;
        for (int i = ch * 25; i < ch * 25 + 25; ++i) {
            float v = Hs[i * HD + col];
            mean += v;
            if (mk2[i] > 0.f && v > mx) mx = v;
        }
        zrd[tid] = mean; CB[tid] = mx;
    }
    __syncthreads();
    if (tid < HD) {
        float mean = zrd[tid] + zrd[128 + tid] + zrd[256 + tid] + zrd[384 + tid];
        float mx = fmaxf(fmaxf(CB[tid], CB[128 + tid]), fmaxf(CB[256 + tid], CB[384 + tid]));
        zsh[tid] += mean * (1.f / KP2);
        zsh[HD + tid] += mx;
    }
    __syncthreads();

    // ---------- P6: MLP + log_softmax (z1 -> CB[0:128], z2 -> CB[256:288]) ----------
    {   // l1: 256 -> 128, k split over 4 chunks of 64
        const int j = tid & 127, q = tid >> 7;
        float a = 0.f;
        for (int kk = 0; kk < 64; ++kk) {
            int k = q * 64 + kk;
            a += zsh[k] * l1w[k * HD + j];
        }
        zrd[tid] = a;
    }
    __syncthreads();
    if (tid < HD)
        CB[tid] = fmaxf(zrd[tid] + zrd[128 + tid] + zrd[256 + tid] + zrd[384 + tid] + l1b[tid], 0.f);
    __syncthreads();
    if (tid < 256) {   // l2: 128 -> 32, k split over 8 chunks of 16
        const int o = tid & 31, q = tid >> 5;
        float a = 0.f;
        for (int kk = 0; kk < 16; ++kk) {
            int k = q * 16 + kk;
            a += CB[k] * l2w[k * 32 + o];
        }
        zrd[tid] = a;
    }
    __syncthreads();
    if (tid < 32) {
        float v = l2b[tid];
#pragma unroll
        for (int q = 0; q < 8; ++q) v += zrd[q * 32 + tid];
        CB[256 + tid] = fmaxf(v, 0.f);
    }
    __syncthreads();
    if (tid == 0) {
        float o0 = l3b[0], o1 = l3b[1];
        for (int k = 0; k < 32; ++k) {
            float v = CB[256 + k];
            o0 += v * l3w[2 * k];
            o1 += v * l3w[2 * k + 1];
        }
        float m = fmaxf(o0, o1);
        float l = m + logf(expf(o0 - m) + expf(o1 - m));
        out[g * 2 + 0] = o0 - l;
        out[g * 2 + 1] = o1 - l;
    }
}

extern "C" void kernel_launch(void* const* d_in, const int* in_sizes, int n_in,
                              void* d_out, int out_size, void* d_ws, size_t ws_size,
                              hipStream_t stream)
{
    const float* x      = (const float*)d_in[0];
    const int*   ei     = (const int*)d_in[1];
    const float* Wrel1  = (const float*)d_in[2];
    const float* Wroot1 = (const float*)d_in[3];
    const float* b1     = (const float*)d_in[4];
    const float* p1     = (const float*)d_in[5];
    const float* Wrel2  = (const float*)d_in[6];
    const float* Wroot2 = (const float*)d_in[7];
    const float* b2     = (const float*)d_in[8];
    const float* p2     = (const float*)d_in[9];
    const float* l1w    = (const float*)d_in[10];
    const float* l1b    = (const float*)d_in[11];
    const float* l2w    = (const float*)d_in[12];
    const float* l2b    = (const float*)d_in[13];
    const float* l3w    = (const float*)d_in[14];
    const float* l3b    = (const float*)d_in[15];
    float* out = (float*)d_out;

    (void)hipFuncSetAttribute((const void*)fused_gnn,
                              hipFuncAttributeMaxDynamicSharedMemorySize, SMEM_BYTES);

    fused_gnn<<<dim3(NB), dim3(NT), SMEM_BYTES, stream>>>(
        x, ei, Wrel1, Wroot1, b1, p1, Wrel2, Wroot2, b2, p2,
        l1w, l1b, l2w, l2b, l3w, l3b, out);
}

// Round 13
// 279.877 us; speedup vs baseline: 9.5001x; 1.0176x over previous
//
#include <hip/hip_runtime.h>
#include <math.h>

#define NB 1000      // graphs
#define NN 100       // nodes per graph
#define EPG 1000     // edges per graph
#define FIN 14
#define HD 128
#define KP1 80
#define KP2 64
#define NT 512       // threads per block

// LDS float offsets — 79,912 B total (< 80 KiB -> 2 blocks/CU)
#define O_HS   0                        // [100][128] = 12800
#define O_CB   12800                    // [100][32] = 3200 (alias xg[0:1600], ag[1600:3200] in conv1)
#define O_WL   16000                    // [16][128] = 2048 (W staging slice)
#define O_SS   18048                    // 1000 ushort = 500 floats (CSR sorted sources)
#define O_RP   18548                    // 104 ints: rowptr
#define O_SC   18652                    // 100
#define O_MK1  18752                    // 100
#define O_MK2  18852                    // 100
#define O_P1   18952                    // 128
#define O_P2   19080                    // 128
#define O_ZSH  19208                    // 256
#define O_ZRD  19464                    // 512 floats (ints deg[0:128], pos[128:228] during CSR build)
#define O_INV  19976                    // 2
#define NSM    19978
#define SMEM_BYTES (NSM * 4)            // 79912 B

// Unified occupancy law (fits r5-r12): waves/SIMD =
// min(floor(256_eff/VGPR), 2*blocks_allowed_by_LDS). r12 proved LDS-staged
// weights give VGPR=64 + ZERO spill (global w-loads drove pressure, not acc).
// Its 141.5KB LDS forced 1 block/CU (23%). Here: Wl 16-row slices with
// register prefetch + chunked CB + ushort ssrc -> 79.9KB -> 2 blocks/CU,
// 4 waves/SIMD, same spill-free inner loop.
__global__ __launch_bounds__(NT, 2) void fused_gnn(
    const float* __restrict__ x, const int* __restrict__ ei,
    const float* __restrict__ Wrel1, const float* __restrict__ Wroot1,
    const float* __restrict__ b1, const float* __restrict__ p1,
    const float* __restrict__ Wrel2, const float* __restrict__ Wroot2,
    const float* __restrict__ b2, const float* __restrict__ p2,
    const float* __restrict__ l1w, const float* __restrict__ l1b,
    const float* __restrict__ l2w, const float* __restrict__ l2b,
    const float* __restrict__ l3w, const float* __restrict__ l3b,
    float* __restrict__ out)
{
    extern __shared__ float smf[];
    float* Hs  = smf + O_HS;
    float* CB  = smf + O_CB;
    float* Wl  = smf + O_WL;
    float* xg  = CB;                 // [100][16] (cols 14,15 zero)
    float* ag  = CB + 1600;          // [100][16]
    unsigned short* ssrc = (unsigned short*)(smf + O_SS);
    int*   rowptr = (int*)(smf + O_RP);
    float* sc  = smf + O_SC;
    float* mk1 = smf + O_MK1;
    float* mk2 = smf + O_MK2;
    float* p1s = smf + O_P1;
    float* p2s = smf + O_P2;
    float* zsh = smf + O_ZSH;
    float* zrd = smf + O_ZRD;
    int*   zdi = (int*)(smf + O_ZRD);   // deg[0:128] / pos[128:228] during build
    float* inv = smf + O_INV;

    const int tid = threadIdx.x;
    const int g = blockIdx.x;
    const int bn = g * NN;
    const int* srcp = ei + g * EPG;
    const int* dstp = ei + NB * EPG + g * EPG;

    // ---------- P0a: stage xg, zero ag, p vectors + norms, zero deg ----------
    for (int t = tid; t < 1600; t += NT) {
        int i = t >> 4, f = t & 15;
        xg[t] = (f < FIN) ? x[bn * FIN + i * FIN + f] : 0.f;
        ag[t] = 0.f;
    }
    if (tid < 128) { p1s[tid] = p1[tid]; p2s[tid] = p2[tid]; zdi[tid] = 0; }
    if (tid >= 256 && tid < 320) {
        int l = tid - 256;
        float a = p1[l], b = p1[l + 64];
        float v = a * a + b * b;
        for (int s = 1; s < 64; s <<= 1) v += __shfl_xor(v, s);
        if (l == 0) inv[0] = rsqrtf(v);
    } else if (tid >= 320 && tid < 384) {
        int l = tid - 320;
        float a = p2[l], b = p2[l + 64];
        float v = a * a + b * b;
        for (int s = 1; s < 64; s <<= 1) v += __shfl_xor(v, s);
        if (l == 0) inv[1] = rsqrtf(v);
    }
    __syncthreads();

    // ---------- P0b: CSR build — count ----------
    for (int e = tid; e < EPG; e += NT) {
        int dl = dstp[e] - bn;
        atomicAdd(&zdi[dl], 1);
    }
    __syncthreads();
    // ---------- P0c: exclusive scan via wave shfl (deg[0:128] -> rowptr) ----------
    if (tid < 64) {
        int a = zdi[tid], b = zdi[tid + 64];
        for (int off = 1; off < 64; off <<= 1) { int t = __shfl_up(a, off); if (tid >= off) a += t; }
        int totA = __shfl(a, 63);
        for (int off = 1; off < 64; off <<= 1) { int t = __shfl_up(b, off); if (tid >= off) b += t; }
        b += totA;
        rowptr[tid + 1] = a;          // inclusive -> rowptr[i+1]
        if (tid + 65 <= 103) rowptr[tid + 65] = b;
        if (tid == 0) rowptr[0] = 0;
    }
    __syncthreads();
    if (tid < NN) zdi[128 + tid] = rowptr[tid];       // pos cursors
    __syncthreads();
    // ---------- P0d: CSR scatter (ushort payload) ----------
    for (int e = tid; e < EPG; e += NT) {
        int sl = srcp[e] - bn;
        int dl = dstp[e] - bn;
        int slot = atomicAdd(&zdi[128 + dl], 1);
        ssrc[slot] = (unsigned short)sl;
    }
    __syncthreads();

    // ---------- P1: conv1 agg via CSR: ag[i][f] = sum_in-edges xg[src][f] ----------
    {
        const int f = tid & 15;
        if (f < FIN) {
            for (int i = tid >> 4; i < NN; i += 32) {
                int s0 = rowptr[i], s1 = rowptr[i + 1];
                float s = 0.f;
                for (int sl0 = s0; sl0 < s1; ++sl0)
                    s += xg[(int)ssrc[sl0] * 16 + f];
                ag[i * 16 + f] = s;
            }
        }
    }
    __syncthreads();

    // ---------- P2: h1 = relu(ag@Wrel1 + xg@Wroot1 + b1) ----------
    {
        const int j = tid & 127;
        float wr[FIN], wo[FIN];
#pragma unroll
        for (int k = 0; k < FIN; ++k) { wr[k] = Wrel1[k * HD + j]; wo[k] = Wroot1[k * HD + j]; }
        const float bb = b1[j];
        for (int i = tid >> 7; i < NN; i += 4) {
            float s = bb;
#pragma unroll
            for (int k = 0; k < FIN; ++k)
                s += ag[i * 16 + k] * wr[k] + xg[i * 16 + k] * wo[k];
            Hs[i * HD + j] = fmaxf(s, 0.f);
        }
    }
    __syncthreads();

    // ---------- P3: pool1 score + top-80 + scale + readout1 ----------
    if (tid < 400) {
        const int row = tid >> 2, q = tid & 3;
        float d = 0.f;
        for (int kk = 0; kk < 32; ++kk) {
            int k = q * 32 + ((kk + tid) & 31);
            d += Hs[row * HD + k] * p1s[k];
        }
        d += __shfl_xor(d, 1);
        d += __shfl_xor(d, 2);
        if (q == 0) sc[row] = tanhf(d * inv[0]);
    }
    __syncthreads();
    if (tid < 400) {                    // rank-count, 4 lanes/row
        const int row = tid >> 2, q = tid & 3;
        float si = sc[row]; int cnt = 0;
        for (int j2 = q * 25; j2 < q * 25 + 25; ++j2) cnt += (sc[j2] > si) ? 1 : 0;
        cnt += __shfl_xor(cnt, 1);
        cnt += __shfl_xor(cnt, 2);
        if (q == 0) mk1[row] = (cnt < KP1) ? 1.f : 0.f;
    }
    __syncthreads();
    for (int o = tid; o < NN * HD; o += NT) { int i = o >> 7; Hs[o] *= sc[i] * mk1[i]; }
    __syncthreads();
    {
        const int col = tid & 127, ch = tid >> 7;
        float mean = 0.f, mx = -1e30f;
        for (int i = ch * 25; i < ch * 25 + 25; ++i) {
            float v = Hs[i * HD + col];
            mean += v;
            if (mk1[i] > 0.f && v > mx) mx = v;
        }
        zrd[tid] = mean; CB[tid] = mx;
    }
    __syncthreads();
    if (tid < HD) {
        float mean = zrd[tid] + zrd[128 + tid] + zrd[256 + tid] + zrd[384 + tid];
        float mx = fmaxf(fmaxf(CB[tid], CB[128 + tid]), fmaxf(CB[256 + tid], CB[384 + tid]));
        zsh[tid] = mean * (1.f / KP1);
        zsh[HD + tid] = mx;
    }
    // (combine reads CB/zrd; first write below is Wl / chunk-gather, both
    //  behind barriers)

    // ---------- P4: conv2, W streamed through 16-row LDS slices ----------
    const int tr = tid >> 5, tc = tid & 31;     // 16 row-groups x 32 col-groups
    const int i0 = tr * 7, j0 = tc * 4;

    int rowc[7];                                 // clamped read rows (stores guarded)
#pragma unroll
    for (int r = 0; r < 7; ++r) rowc[r] = (i0 + r < NN) ? (i0 + r) : (NN - 1);

    float acc[7][4];
    {
        float4 bv = ((const float4*)b2)[tc];
#pragma unroll
        for (int r = 0; r < 7; ++r) { acc[r][0] = bv.x; acc[r][1] = bv.y; acc[r][2] = bv.z; acc[r][3] = bv.w; }
    }

    const float4* Wroot2v = (const float4*)Wroot2;
    const float4* Wrel2v  = (const float4*)Wrel2;

#define FMA_SLICE(ABASE, LD, KOFF)                                          \
    for (int k0 = 0; k0 < 16; k0 += 4) {                                    \
        const float* wl = Wl + k0 * HD + j0;                                \
        float4 w0 = *(const float4*)(wl);                                   \
        float4 w1 = *(const float4*)(wl + HD);                              \
        float4 w2 = *(const float4*)(wl + 2 * HD);                          \
        float4 w3 = *(const float4*)(wl + 3 * HD);                          \
        _Pragma("unroll")                                                   \
        for (int r = 0; r < 7; ++r) {                                       \
            float4 a = *(const float4*)&ABASE[rowc[r] * (LD) + (KOFF) + k0];\
            acc[r][0] += a.x * w0.x + a.y * w1.x + a.z * w2.x + a.w * w3.x; \
            acc[r][1] += a.x * w0.y + a.y * w1.y + a.z * w2.y + a.w * w3.y; \
            acc[r][2] += a.x * w0.z + a.y * w1.z + a.z * w2.z + a.w * w3.z; \
            acc[r][3] += a.x * w0.w + a.y * w1.w + a.z * w2.w + a.w * w3.w; \
        }                                                                   \
    }

    // ROOT pass: 8 slices of 16 k-rows; reg-prefetch next slice during FMA
    float4 pre = Wroot2v[tid];                  // slice 0 (1 float4/thread)
    for (int s = 0; s < 8; ++s) {
        __syncthreads();                        // Wl readers of prev slice done
        ((float4*)Wl)[tid] = pre;
        pre = (s < 7) ? Wroot2v[(s + 1) * 512 + tid]   // prefetch next
                      : Wrel2v[tid];                   // or rel slice 0
        __syncthreads();                        // slice visible
        FMA_SLICE(Hs, HD, s * 16)
    }

    // REL pass: 4 chunks of 32 cols; float4 CSR gather, then 2 slices each
    for (int c = 0; c < 4; ++c) {
        __syncthreads();                        // CB readers (prev chunk) done
        for (int t = tid; t < 800; t += NT) {   // 100 rows x 8 col-groups
            int i = t >> 3, jj = t & 7;
            int s0 = rowptr[i], s1 = rowptr[i + 1];
            float4 s = {0.f, 0.f, 0.f, 0.f};
            for (int e = s0; e < s1; ++e) {
                const float4 v = *(const float4*)&Hs[(int)ssrc[e] * HD + c * 32 + jj * 4];
                s.x += v.x; s.y += v.y; s.z += v.z; s.w += v.w;
            }
            *(float4*)&CB[i * 32 + jj * 4] = s;
        }
        for (int s2 = 0; s2 < 2; ++s2) {
            __syncthreads();                    // Wl readers done (+ gather done at s2=0)
            ((float4*)Wl)[tid] = pre;
            int nxt = c * 2 + s2 + 1;
            if (nxt < 8) pre = Wrel2v[nxt * 512 + tid];
            __syncthreads();                    // slice visible
            FMA_SLICE(CB, 32, s2 * 16)
        }
    }
    __syncthreads();                            // all reads of Hs/CB/Wl done

    // write h2 = relu(acc) into Hs, guarded
#pragma unroll
    for (int r = 0; r < 7; ++r) {
        if (i0 + r < NN) {
            float4 v;
            v.x = fmaxf(acc[r][0], 0.f); v.y = fmaxf(acc[r][1], 0.f);
            v.z = fmaxf(acc[r][2], 0.f); v.w = fmaxf(acc[r][3], 0.f);
            *(float4*)&Hs[(i0 + r) * HD + j0] = v;
        }
    }
    __syncthreads();

    // ---------- P5: pool2 + readout2 ----------
    if (tid < 400) {
        const int row = tid >> 2, q = tid & 3;
        float d = 0.f;
        for (int kk = 0; kk < 32; ++kk) {
            int k = q * 32 + ((kk + tid) & 31);
            d += Hs[row * HD + k] * p2s[k];
        }
        d += __shfl_xor(d, 1);
        d += __shfl_xor(d, 2);
        if (q == 0) sc[row] = (mk1[row] > 0.f) ? tanhf(d * inv[1]) : -1e30f;
    }
    __syncthreads();
    if (tid < 400) {                    // rank-count, 4 lanes/row
        const int row = tid >> 2, q = tid & 3;
        float si = sc[row]; int cnt = 0;
        for (int j2 = q * 25; j2 < q * 25 + 25; ++j2) cnt += (sc[j2] > si) ? 1 : 0;
        cnt += __shfl_xor(cnt, 1);
        cnt += __shfl_xor(cnt, 2);
        if (q == 0) mk2[row] = (mk1[row] > 0.f && cnt < KP2) ? 1.f : 0.f;
    }
    __syncthreads();
    for (int o = tid; o < NN * HD; o += NT) { int i = o >> 7; Hs[o] *= sc[i] * mk2[i]; }
    __syncthreads();
    {
        const int col = tid & 127, ch = tid >> 7;
        float mean = 0.f, mx = -1e30f;
        for (int i = ch * 25; i < ch * 25 + 25; ++i) {
            float v = Hs[i * HD + col];
            mean += v;
            if (mk2[i] > 0.f && v > mx) mx = v;
        }
        zrd[tid] = mean; CB[tid] = mx;
    }
    __syncthreads();
    if (tid < HD) {
        float mean = zrd[tid] + zrd[128 + tid] + zrd[256 + tid] + zrd[384 + tid];
        float mx = fmaxf(fmaxf(CB[tid], CB[128 + tid]), fmaxf(CB[256 + tid], CB[384 + tid]));
        zsh[tid] += mean * (1.f / KP2);
        zsh[HD + tid] += mx;
    }
    __syncthreads();

    // ---------- P6: MLP + log_softmax (z1 -> CB[0:128], z2 -> CB[256:288]) ----------
    {   // l1: 256 -> 128, k split over 4 chunks of 64
        const int j = tid & 127, q = tid >> 7;
        float a = 0.f;
        for (int kk = 0; kk < 64; ++kk) {
            int k = q * 64 + kk;
            a += zsh[k] * l1w[k * HD + j];
        }
        zrd[tid] = a;
    }
    __syncthreads();
    if (tid < HD)
        CB[tid] = fmaxf(zrd[tid] + zrd[128 + tid] + zrd[256 + tid] + zrd[384 + tid] + l1b[tid], 0.f);
    __syncthreads();
    if (tid < 256) {   // l2: 128 -> 32, k split over 8 chunks of 16
        const int o = tid & 31, q = tid >> 5;
        float a = 0.f;
        for (int kk = 0; kk < 16; ++kk) {
            int k = q * 16 + kk;
            a += CB[k] * l2w[k * 32 + o];
        }
        zrd[tid] = a;
    }
    __syncthreads();
    if (tid < 32) {
        float v = l2b[tid];
#pragma unroll
        for (int q = 0; q < 8; ++q) v += zrd[q * 32 + tid];
        CB[256 + tid] = fmaxf(v, 0.f);
    }
    __syncthreads();
    if (tid == 0) {
        float o0 = l3b[0], o1 = l3b[1];
        for (int k = 0; k < 32; ++k) {
            float v = CB[256 + k];
            o0 += v * l3w[2 * k];
            o1 += v * l3w[2 * k + 1];
        }
        float m = fmaxf(o0, o1);
        float l = m + logf(expf(o0 - m) + expf(o1 - m));
        out[g * 2 + 0] = o0 - l;
        out[g * 2 + 1] = o1 - l;
    }
}

extern "C" void kernel_launch(void* const* d_in, const int* in_sizes, int n_in,
                              void* d_out, int out_size, void* d_ws, size_t ws_size,
                              hipStream_t stream)
{
    const float* x      = (const float*)d_in[0];
    const int*   ei     = (const int*)d_in[1];
    const float* Wrel1  = (const float*)d_in[2];
    const float* Wroot1 = (const float*)d_in[3];
    const float* b1     = (const float*)d_in[4];
    const float* p1     = (const float*)d_in[5];
    const float* Wrel2  = (const float*)d_in[6];
    const float* Wroot2 = (const float*)d_in[7];
    const float* b2     = (const float*)d_in[8];
    const float* p2     = (const float*)d_in[9];
    const float* l1w    = (const float*)d_in[10];
    const float* l1b    = (const float*)d_in[11];
    const float* l2w    = (const float*)d_in[12];
    const float* l2b    = (const float*)d_in[13];
    const float* l3w    = (const float*)d_in[14];
    const float* l3b    = (const float*)d_in[15];
    float* out = (float*)d_out;

    (void)hipFuncSetAttribute((const void*)fused_gnn,
                              hipFuncAttributeMaxDynamicSharedMemorySize, SMEM_BYTES);

    fused_gnn<<<dim3(NB), dim3(NT), SMEM_BYTES, stream>>>(
        x, ei, Wrel1, Wroot1, b1, p1, Wrel2, Wroot2, b2, p2,
        l1w, l1b, l2w, l2b, l3w, l3b, out);
}